// Round 6
// baseline (402.269 us; speedup 1.0000x reference)
//
#include <hip/hip_runtime.h>
#include <hip/hip_fp16.h>

// GCN autoencoder, R13: two-phase bucketed CSR build.
// R12's scatter_part was 84us: 8x dst re-read (50MB fetch) + csr line churn
// (64MB write for ~13MB dirty) from interleaving streaming reads with random
// appends in the same L2. Now: phase A reads edges ONCE, buckets into 8
// per-partition queues (packed 4B entries, coalesced writes); phase B streams
// each queue on its own XCD and appends into XCD-local cur/csr, so dirty csr
// lines are written back once. Queues overlay sA (dead until layer 1).
// Fused MFMA layers unchanged from R12.

typedef _Float16 f16x8 __attribute__((ext_vector_type(8)));
typedef float f32x4 __attribute__((ext_vector_type(4)));

static inline size_t align256(size_t x) { return (x + 255) & ~(size_t)255; }

constexpr int PAD = 64;  // csr slots per node (Poisson(16) max-deg ~44)

// ---- Phase A: bucket edges by dst partition ----
// Block = 4096-edge chunk. Pack (d_local<<17)|src into queue[p] (4B/edge).
// d_local < ceil(n/8)=12500 (14 bits), src < 131072 (17 bits).
__global__ void __launch_bounds__(256) bucket_kernel(
        const int* __restrict__ src, const int* __restrict__ dst, int E, int n,
        int* __restrict__ qcnt, int* __restrict__ queue, int qcap) {
    __shared__ int hist[8][16];
    __shared__ int gbase[8];
    __shared__ int cursor[8];
    const int tid = threadIdx.x;
    if (tid < 128) ((int*)hist)[tid] = 0;
    if (tid < 8) cursor[tid] = 0;
    __syncthreads();

    const int e0 = blockIdx.x * 4096;
    int s[16], dl[16], p[16];
    bool v[16];
#pragma unroll
    for (int l = 0; l < 16; ++l) {
        int e = e0 + l * 256 + tid;
        v[l] = e < E;
        int d  = v[l] ? __builtin_nontemporal_load(dst + e) : 0;
        int ss = v[l] ? __builtin_nontemporal_load(src + e) : 0;
        int pp = (int)(((long long)d * 8) / n);
        int lo = (int)(((long long)n * pp + 7) >> 3);   // first node of partition pp
        p[l] = pp; dl[l] = d - lo; s[l] = ss;
        if (v[l]) atomicAdd(&hist[pp][tid & 15], 1);
    }
    __syncthreads();
    if (tid < 8) {
        int t = 0;
#pragma unroll
        for (int k = 0; k < 16; ++k) t += hist[tid][k];
        gbase[tid] = t ? atomicAdd(&qcnt[tid], t) : 0;
    }
    __syncthreads();
#pragma unroll
    for (int l = 0; l < 16; ++l) {
        if (v[l]) {
            int pp = p[l];
            int r = atomicAdd(&cursor[pp], 1) + gbase[pp];
            if (r < qcap) queue[(size_t)pp * qcap + r] = (dl[l] << 17) | s[l];
        }
    }
}

// ---- Phase B: per-partition append into XCD-local cur/csr ----
// Block b: partition b&7 (round-robin blockIdx->XCD), sub-block b>>3.
__global__ void __launch_bounds__(256) scatter_q_kernel(
        const int* __restrict__ qcnt, const int* __restrict__ queue, int qcap,
        int n, int* __restrict__ cur, int* __restrict__ csr) {
    const int p = blockIdx.x & 7;
    const int sb = blockIdx.x >> 3;
    const int nsb = gridDim.x >> 3;
    const int lo = (int)(((long long)n * p + 7) >> 3);
    const int qn = qcnt[p];
    const int* q = queue + (size_t)p * qcap;
    for (int i = sb * 1024 + (int)threadIdx.x * 4; i < qn; i += nsb * 1024) {
        int4 u4 = *(const int4*)&q[i];      // 16B coalesced; tail ints masked below
        int uu[4] = {u4.x, u4.y, u4.z, u4.w};
#pragma unroll
        for (int k = 0; k < 4; ++k) {
            if (i + k < qn) {
                int s = uu[k] & 0x1FFFF;
                int d = lo + (uu[k] >> 17);
                int pos = atomicAdd(&cur[d], 1);
                if (pos < PAD) csr[(size_t)d * PAD + pos] = s;
            }
        }
    }
}

// dinv[i] = rsqrt(deg+1); xh[i,:] = (half)(dinv[i] * x[i,:])
__global__ void scale_cast_kernel(const float* __restrict__ x, const int* __restrict__ cnt,
                                  float* __restrict__ dinv, __half* __restrict__ xh, int n) {
    int t = blockIdx.x * blockDim.x + threadIdx.x;   // over n*16 float4s
    if (t >= n * 16) return;
    int node = t >> 4;
    float d = rsqrtf((float)cnt[node] + 1.0f);
    if ((t & 15) == 0) dinv[node] = d;
    float4 v = ((const float4*)x)[t];
    __half2* o = (__half2*)xh;
    o[t * 2 + 0] = __floats2half2_rn(v.x * d, v.y * d);
    o[t * 2 + 1] = __floats2half2_rn(v.z * d, v.w * d);
}

__device__ __forceinline__ void accum8(float4& a0, float4& a1, const uint4& u, float w) {
    const __half2* h = reinterpret_cast<const __half2*>(&u);
    float2 f0 = __half22float2(h[0]);
    float2 f1 = __half22float2(h[1]);
    float2 f2 = __half22float2(h[2]);
    float2 f3 = __half22float2(h[3]);
    a0.x = fmaf(w, f0.x, a0.x); a0.y = fmaf(w, f0.y, a0.y);
    a0.z = fmaf(w, f1.x, a0.z); a0.w = fmaf(w, f1.y, a0.w);
    a1.x = fmaf(w, f2.x, a1.x); a1.y = fmaf(w, f2.y, a1.y);
    a1.z = fmaf(w, f3.x, a1.z); a1.w = fmaf(w, f3.y, a1.w);
}

// Fused GCN layer, prescaled fp16 input, padded CSR, MFMA epilogue (as R12).
template <int K, int M, bool RELU, bool WS, bool WR>
__global__ void __launch_bounds__(256) fused_mfma(
        const __half* __restrict__ in, const float* __restrict__ W,
        const float* __restrict__ bias,
        const int* __restrict__ cnt, const int* __restrict__ csr,
        const float* __restrict__ dinv,
        __half* __restrict__ outS, float* __restrict__ outR, int n) {
    constexpr int LPR = K / 8;       // lanes per feature row (uint4 = 8 halves)
    constexpr int GRP = 64 / LPR;    // nodes per gather round (8 or 16)
    constexpr int ROUNDS = 16 / GRP; // rounds to fill 16-node batch (2 or 1)
    constexpr int KT = K / 32;       // MFMA K-tiles
    constexpr int NT = M / 16;       // MFMA N-tiles
    constexpr int KP = K + 8;        // padded row (16B-aligned, bank-spread)

    __shared__ _Float16 Wht[M][KP];          // W transposed, fp16
    __shared__ alignas(16) float aS[4][16][KP];  // per-wave 16-node accum

    const int wv = threadIdx.x >> 6, lane = threadIdx.x & 63;

    // stage W transposed+fp16 into LDS (coalesced global reads), once/block
    for (int t = threadIdx.x; t < K * M; t += 256) {
        int k = t / M, j = t % M;
        Wht[j][k] = (_Float16)W[t];
    }
    __syncthreads();   // all waves reach this before any early-out

    const int i0 = (blockIdx.x * 4 + wv) * 16;
    if (i0 >= n) return;             // n % 16 == 0: active waves fully in-bounds

    const int g = lane / LPR, sub = lane % LPR;
    const uint4* in16 = (const uint4*)in;

#pragma unroll
    for (int r = 0; r < ROUNDS; ++r) {
        const int node = i0 + r * GRP + g;       // this group's node
        const int deg = min(cnt[node], PAD);
        const float dv = dinv[node];
        const int base = node * PAD;
        float4 a0 = make_float4(0.f, 0.f, 0.f, 0.f), a1 = a0;
        accum8(a0, a1, in16[(size_t)node * LPR + sub], 1.0f);  // self loop

#define GSTEP(SLOT, SIDX)                                                   \
        {                                                                   \
            bool m_ = (SLOT) < deg;                                         \
            int si = m_ ? (SIDX) : node;  /* dummy: own row, L1-hot */      \
            uint4 v = in16[(size_t)si * LPR + sub];                         \
            accum8(a0, a1, v, m_ ? 1.0f : 0.0f);                            \
        }
        // fixed 32 slots, fully unrolled (indices independent -> deep MLP)
#pragma unroll
        for (int t = 0; t < 8; ++t) {
            int4 idx = *(const int4*)&csr[base + t * 4];
            GSTEP(t * 4 + 0, idx.x)
            GSTEP(t * 4 + 1, idx.y)
            GSTEP(t * 4 + 2, idx.z)
            GSTEP(t * 4 + 3, idx.w)
        }
        // rare tail: deg > 32 (P ~ 1.5e-4 per node)
        for (int t = 8; t < 16; ++t) {
            if (!__any(t * 4 < deg)) break;
            int4 idx = *(const int4*)&csr[base + t * 4];
            GSTEP(t * 4 + 0, idx.x)
            GSTEP(t * 4 + 1, idx.y)
            GSTEP(t * 4 + 2, idx.z)
            GSTEP(t * 4 + 3, idx.w)
        }
#undef GSTEP
        // fold dinv[dst]; write lane-local accum to batch buffer
        a0.x *= dv; a0.y *= dv; a0.z *= dv; a0.w *= dv;
        a1.x *= dv; a1.y *= dv; a1.z *= dv; a1.w *= dv;
        *(float4*)&aS[wv][r * GRP + g][sub * 8] = a0;
        *(float4*)&aS[wv][r * GRP + g][sub * 8 + 4] = a1;
    }
    // per-wave LDS: compiler inserts lgkmcnt waits; no barrier needed

    // ---- MFMA epilogue: y[16 x M] = aS[16 x K] @ W[K x M] ----
    const int mm = lane & 15, q = lane >> 4;
    f32x4 acc[NT];
#pragma unroll
    for (int nt = 0; nt < NT; ++nt) acc[nt] = (f32x4){0.f, 0.f, 0.f, 0.f};
#pragma unroll
    for (int kt = 0; kt < KT; ++kt) {
        float4 af0 = *(const float4*)&aS[wv][mm][kt * 32 + q * 8];
        float4 af1 = *(const float4*)&aS[wv][mm][kt * 32 + q * 8 + 4];
        f16x8 a;
        a[0] = (_Float16)af0.x; a[1] = (_Float16)af0.y;
        a[2] = (_Float16)af0.z; a[3] = (_Float16)af0.w;
        a[4] = (_Float16)af1.x; a[5] = (_Float16)af1.y;
        a[6] = (_Float16)af1.z; a[7] = (_Float16)af1.w;
#pragma unroll
        for (int nt = 0; nt < NT; ++nt) {
            f16x8 b = *(const f16x8*)&Wht[nt * 16 + mm][kt * 32 + q * 8];
            acc[nt] = __builtin_amdgcn_mfma_f32_16x16x32_f16(a, b, acc[nt], 0, 0, 0);
        }
    }

    float dv4[4];
    if constexpr (WS) {
#pragma unroll
        for (int r = 0; r < 4; ++r) dv4[r] = dinv[i0 + q * 4 + r];
    }
#pragma unroll
    for (int nt = 0; nt < NT; ++nt) {
        float bv = bias[nt * 16 + mm];
#pragma unroll
        for (int r = 0; r < 4; ++r) {
            int node = i0 + q * 4 + r;
            float y = acc[nt][r] + bv;
            if (RELU) y = fmaxf(y, 0.0f);
            if (WR) outR[(size_t)node * M + nt * 16 + mm] = y;
            if (WS) outS[(size_t)node * M + nt * 16 + mm] = __float2half_rn(dv4[r] * y);
        }
    }
}

extern "C" void kernel_launch(void* const* d_in, const int* in_sizes, int n_in,
                              void* d_out, int out_size, void* d_ws, size_t ws_size,
                              hipStream_t stream) {
    (void)n_in; (void)out_size; (void)ws_size;

    const float* x  = (const float*)d_in[0];
    const int*   ei = (const int*)d_in[1];
    const float* W1 = (const float*)d_in[2];  const float* b1 = (const float*)d_in[3];
    const float* W2 = (const float*)d_in[4];  const float* b2 = (const float*)d_in[5];
    const float* W3 = (const float*)d_in[6];  const float* b3 = (const float*)d_in[7];
    const float* W4 = (const float*)d_in[8];  const float* b4 = (const float*)d_in[9];
    const float* W5 = (const float*)d_in[10]; const float* b5 = (const float*)d_in[11];
    const float* W6 = (const float*)d_in[12]; const float* b6 = (const float*)d_in[13];

    const int n = in_sizes[0] / 64;   // 100000
    const int E = in_sizes[1] / 2;    // 1600000
    const int* src = ei;
    const int* dst = ei + E;

    float* out  = (float*)d_out;
    float* xrec = out;                       // [n,64]
    float* z    = out + (size_t)n * 64;      // [n,32]

    char* ws = (char*)d_ws;
    size_t off = 0;
    float*  dinv = (float*)(ws + off);  off += align256((size_t)n * 4);
    int*    cur  = (int*)(ws + off);    off += align256((size_t)(n + 8) * 4);
    int*    csr  = (int*)(ws + off);    off += align256((size_t)n * PAD * 4);
    __half* sA   = (__half*)(ws + off); off += align256((size_t)n * 64 * 2);
    __half* sB   = (__half*)(ws + off); off += align256((size_t)n * 64 * 2);
    __half* sZ   = (__half*)(ws + off); off += align256((size_t)n * 32 * 2);
    __half* xh   = sB;       // overlay: xh dead after layer 1
    int*    qcnt = cur + n;  // 8 ints in cur's allocation, zeroed by same memset
    int*    queue = (int*)sA;               // overlay: dead before layer 1 writes sA
    const int qcap = E / 8 + 16384;         // 8*qcap*4 = 6.9MB <= sizeof(sA)

    const int B = 256;
    const int fGrid = (n + 63) / 64;          // 16 nodes/wave, 4 waves/block
    const int nch = (E + 4095) / 4096;

    // ---- CSR build: bucket -> per-XCD append -> prescale ----
    hipMemsetAsync(cur, 0, (size_t)(n + 8) * 4, stream);
    bucket_kernel<<<nch, B, 0, stream>>>(src, dst, E, n, qcnt, queue, qcap);
    scatter_q_kernel<<<8 * 64, B, 0, stream>>>(qcnt, queue, qcap, n, cur, csr);
    scale_cast_kernel<<<(n * 16 + B - 1) / B, B, 0, stream>>>(x, cur, dinv, xh, n);

    // ---- Layer 1: relu((A x) W1 + b1) -> sA (prescaled fp16) ----
    fused_mfma<64, 64, true, true, false><<<fGrid, B, 0, stream>>>(
        xh, W1, b1, cur, csr, dinv, sA, nullptr, n);
    // ---- Layer 2 -> sB ----
    fused_mfma<64, 64, true, true, false><<<fGrid, B, 0, stream>>>(
        sA, W2, b2, cur, csr, dinv, sB, nullptr, n);
    // ---- Layer 3: 64->32, no relu; z fp32 + prescaled sZ ----
    fused_mfma<64, 32, false, true, true><<<fGrid, B, 0, stream>>>(
        sB, W3, b3, cur, csr, dinv, sZ, z, n);
    // ---- Layer 4: 32->64 relu -> sA ----
    fused_mfma<32, 64, true, true, false><<<fGrid, B, 0, stream>>>(
        sZ, W4, b4, cur, csr, dinv, sA, nullptr, n);
    // ---- Layer 5 -> sB ----
    fused_mfma<64, 64, true, true, false><<<fGrid, B, 0, stream>>>(
        sA, W5, b5, cur, csr, dinv, sB, nullptr, n);
    // ---- Layer 6: no relu -> xrec (fp32) ----
    fused_mfma<64, 64, false, false, true><<<fGrid, B, 0, stream>>>(
        sB, W6, b6, cur, csr, dinv, nullptr, xrec, n);
}

// Round 7
// 353.931 us; speedup vs baseline: 1.1366x; 1.1366x over previous
//
#include <hip/hip_runtime.h>
#include <hip/hip_fp16.h>

// GCN autoencoder, R14: CSR build with NO per-edge global atomics.
// R13's scatter_q was 71us with WRITE_SIZE 64MB ~= 40B/edge of fabric
// traffic -- device-scope atomicAdd per edge executes at the cross-XCD
// coherence point, so each RMW is a fabric round-trip no matter how csr
// lines are arranged. Now: phase A bins edges into 256 node-range buckets
// (LDS hist + one global reservation per block*bucket = 100K atomics);
// phase B = one block per bucket, per-node counters in LDS (on-CU atomics),
// plain stores into the block-private csr region, cur[] written from the
// LDS histogram (no cur memset needed). Fused MFMA layers unchanged (R12).

typedef _Float16 f16x8 __attribute__((ext_vector_type(8)));
typedef float f32x4 __attribute__((ext_vector_type(4)));

static inline size_t align256(size_t x) { return (x + 255) & ~(size_t)255; }

constexpr int PAD = 64;   // csr slots per node (Poisson(16) max-deg ~44)
constexpr int NB  = 256;  // dst buckets (~391 nodes each)

// ---- Phase A: bucket edges by dst range ----
// Block = 4096-edge chunk. Pack (d_local<<17)|src (d_local<512, src<2^17).
__global__ void __launch_bounds__(256) bucket_kernel(
        const int* __restrict__ src, const int* __restrict__ dst, int E, int BW,
        int* __restrict__ qcnt, int* __restrict__ queue, int qcap) {
    __shared__ int hist[NB];
    __shared__ int gbase[NB];
    __shared__ int cursor[NB];
    const int tid = threadIdx.x;
    hist[tid] = 0; cursor[tid] = 0;          // blockDim == NB == 256
    __syncthreads();

    const int e0 = blockIdx.x * 4096;
    int pk[16], bk[16];
#pragma unroll
    for (int l = 0; l < 16; ++l) {
        int e = e0 + l * 256 + tid;
        bool v = e < E;
        int d = v ? __builtin_nontemporal_load(dst + e) : 0;
        int s = v ? __builtin_nontemporal_load(src + e) : 0;
        int b = (int)((unsigned)d / (unsigned)BW);
        pk[l] = ((d - b * BW) << 17) | s;
        bk[l] = v ? b : -1;
        if (v) atomicAdd(&hist[b], 1);       // LDS
    }
    __syncthreads();
    int h = hist[tid];
    gbase[tid] = h ? atomicAdd(&qcnt[tid], h) : 0;   // 1 global atomic/bucket
    __syncthreads();
#pragma unroll
    for (int l = 0; l < 16; ++l) {
        if (bk[l] >= 0) {
            int b = bk[l];
            int r = gbase[b] + atomicAdd(&cursor[b], 1);   // LDS
            if (r < qcap) queue[(size_t)b * qcap + r] = pk[l];
        }
    }
}

// ---- Phase B: one block per bucket, LDS counters, plain csr stores ----
__global__ void __launch_bounds__(256) scatter_lds_kernel(
        const int* __restrict__ qcnt, const int* __restrict__ queue, int qcap,
        int n, int BW, int* __restrict__ cur, int* __restrict__ csr) {
    __shared__ int cnt[512];                 // BW <= 512
    const int b = blockIdx.x;
    const int node0 = b * BW;
    const int nn = min(BW, n - node0);
    if (nn <= 0) return;
    for (int t = threadIdx.x; t < nn; t += 256) cnt[t] = 0;
    __syncthreads();
    const int qn = min(qcnt[b], qcap);
    const int* q = queue + (size_t)b * qcap;
    for (int i = threadIdx.x; i < qn; i += 256) {
        int u = q[i];
        int dl = u >> 17;
        int s = u & 0x1FFFF;
        int pos = atomicAdd(&cnt[dl], 1);    // LDS, on-CU
        if (pos < PAD) csr[(size_t)(node0 + dl) * PAD + pos] = s;
    }
    __syncthreads();
    for (int t = threadIdx.x; t < nn; t += 256) cur[node0 + t] = cnt[t];
}

// dinv[i] = rsqrt(deg+1); xh[i,:] = (half)(dinv[i] * x[i,:])
__global__ void scale_cast_kernel(const float* __restrict__ x, const int* __restrict__ cnt,
                                  float* __restrict__ dinv, __half* __restrict__ xh, int n) {
    int t = blockIdx.x * blockDim.x + threadIdx.x;   // over n*16 float4s
    if (t >= n * 16) return;
    int node = t >> 4;
    float d = rsqrtf((float)cnt[node] + 1.0f);
    if ((t & 15) == 0) dinv[node] = d;
    float4 v = ((const float4*)x)[t];
    __half2* o = (__half2*)xh;
    o[t * 2 + 0] = __floats2half2_rn(v.x * d, v.y * d);
    o[t * 2 + 1] = __floats2half2_rn(v.z * d, v.w * d);
}

__device__ __forceinline__ void accum8(float4& a0, float4& a1, const uint4& u, float w) {
    const __half2* h = reinterpret_cast<const __half2*>(&u);
    float2 f0 = __half22float2(h[0]);
    float2 f1 = __half22float2(h[1]);
    float2 f2 = __half22float2(h[2]);
    float2 f3 = __half22float2(h[3]);
    a0.x = fmaf(w, f0.x, a0.x); a0.y = fmaf(w, f0.y, a0.y);
    a0.z = fmaf(w, f1.x, a0.z); a0.w = fmaf(w, f1.y, a0.w);
    a1.x = fmaf(w, f2.x, a1.x); a1.y = fmaf(w, f2.y, a1.y);
    a1.z = fmaf(w, f3.x, a1.z); a1.w = fmaf(w, f3.y, a1.w);
}

// Fused GCN layer, prescaled fp16 input, padded CSR, MFMA epilogue (as R12).
template <int K, int M, bool RELU, bool WS, bool WR>
__global__ void __launch_bounds__(256) fused_mfma(
        const __half* __restrict__ in, const float* __restrict__ W,
        const float* __restrict__ bias,
        const int* __restrict__ cnt, const int* __restrict__ csr,
        const float* __restrict__ dinv,
        __half* __restrict__ outS, float* __restrict__ outR, int n) {
    constexpr int LPR = K / 8;       // lanes per feature row (uint4 = 8 halves)
    constexpr int GRP = 64 / LPR;    // nodes per gather round (8 or 16)
    constexpr int ROUNDS = 16 / GRP; // rounds to fill 16-node batch (2 or 1)
    constexpr int KT = K / 32;       // MFMA K-tiles
    constexpr int NT = M / 16;       // MFMA N-tiles
    constexpr int KP = K + 8;        // padded row (16B-aligned, bank-spread)

    __shared__ _Float16 Wht[M][KP];          // W transposed, fp16
    __shared__ alignas(16) float aS[4][16][KP];  // per-wave 16-node accum

    const int wv = threadIdx.x >> 6, lane = threadIdx.x & 63;

    // stage W transposed+fp16 into LDS (coalesced global reads), once/block
    for (int t = threadIdx.x; t < K * M; t += 256) {
        int k = t / M, j = t % M;
        Wht[j][k] = (_Float16)W[t];
    }
    __syncthreads();   // all waves reach this before any early-out

    const int i0 = (blockIdx.x * 4 + wv) * 16;
    if (i0 >= n) return;             // n % 16 == 0: active waves fully in-bounds

    const int g = lane / LPR, sub = lane % LPR;
    const uint4* in16 = (const uint4*)in;

#pragma unroll
    for (int r = 0; r < ROUNDS; ++r) {
        const int node = i0 + r * GRP + g;       // this group's node
        const int deg = min(cnt[node], PAD);
        const float dv = dinv[node];
        const int base = node * PAD;
        float4 a0 = make_float4(0.f, 0.f, 0.f, 0.f), a1 = a0;
        accum8(a0, a1, in16[(size_t)node * LPR + sub], 1.0f);  // self loop

#define GSTEP(SLOT, SIDX)                                                   \
        {                                                                   \
            bool m_ = (SLOT) < deg;                                         \
            int si = m_ ? (SIDX) : node;  /* dummy: own row, L1-hot */      \
            uint4 v = in16[(size_t)si * LPR + sub];                         \
            accum8(a0, a1, v, m_ ? 1.0f : 0.0f);                            \
        }
        // fixed 32 slots, fully unrolled (indices independent -> deep MLP)
#pragma unroll
        for (int t = 0; t < 8; ++t) {
            int4 idx = *(const int4*)&csr[base + t * 4];
            GSTEP(t * 4 + 0, idx.x)
            GSTEP(t * 4 + 1, idx.y)
            GSTEP(t * 4 + 2, idx.z)
            GSTEP(t * 4 + 3, idx.w)
        }
        // rare tail: deg > 32 (P ~ 1.5e-4 per node)
        for (int t = 8; t < 16; ++t) {
            if (!__any(t * 4 < deg)) break;
            int4 idx = *(const int4*)&csr[base + t * 4];
            GSTEP(t * 4 + 0, idx.x)
            GSTEP(t * 4 + 1, idx.y)
            GSTEP(t * 4 + 2, idx.z)
            GSTEP(t * 4 + 3, idx.w)
        }
#undef GSTEP
        // fold dinv[dst]; write lane-local accum to batch buffer
        a0.x *= dv; a0.y *= dv; a0.z *= dv; a0.w *= dv;
        a1.x *= dv; a1.y *= dv; a1.z *= dv; a1.w *= dv;
        *(float4*)&aS[wv][r * GRP + g][sub * 8] = a0;
        *(float4*)&aS[wv][r * GRP + g][sub * 8 + 4] = a1;
    }
    // per-wave LDS: compiler inserts lgkmcnt waits; no barrier needed

    // ---- MFMA epilogue: y[16 x M] = aS[16 x K] @ W[K x M] ----
    const int mm = lane & 15, q = lane >> 4;
    f32x4 acc[NT];
#pragma unroll
    for (int nt = 0; nt < NT; ++nt) acc[nt] = (f32x4){0.f, 0.f, 0.f, 0.f};
#pragma unroll
    for (int kt = 0; kt < KT; ++kt) {
        float4 af0 = *(const float4*)&aS[wv][mm][kt * 32 + q * 8];
        float4 af1 = *(const float4*)&aS[wv][mm][kt * 32 + q * 8 + 4];
        f16x8 a;
        a[0] = (_Float16)af0.x; a[1] = (_Float16)af0.y;
        a[2] = (_Float16)af0.z; a[3] = (_Float16)af0.w;
        a[4] = (_Float16)af1.x; a[5] = (_Float16)af1.y;
        a[6] = (_Float16)af1.z; a[7] = (_Float16)af1.w;
#pragma unroll
        for (int nt = 0; nt < NT; ++nt) {
            f16x8 b = *(const f16x8*)&Wht[nt * 16 + mm][kt * 32 + q * 8];
            acc[nt] = __builtin_amdgcn_mfma_f32_16x16x32_f16(a, b, acc[nt], 0, 0, 0);
        }
    }

    float dv4[4];
    if constexpr (WS) {
#pragma unroll
        for (int r = 0; r < 4; ++r) dv4[r] = dinv[i0 + q * 4 + r];
    }
#pragma unroll
    for (int nt = 0; nt < NT; ++nt) {
        float bv = bias[nt * 16 + mm];
#pragma unroll
        for (int r = 0; r < 4; ++r) {
            int node = i0 + q * 4 + r;
            float y = acc[nt][r] + bv;
            if (RELU) y = fmaxf(y, 0.0f);
            if (WR) outR[(size_t)node * M + nt * 16 + mm] = y;
            if (WS) outS[(size_t)node * M + nt * 16 + mm] = __float2half_rn(dv4[r] * y);
        }
    }
}

extern "C" void kernel_launch(void* const* d_in, const int* in_sizes, int n_in,
                              void* d_out, int out_size, void* d_ws, size_t ws_size,
                              hipStream_t stream) {
    (void)n_in; (void)out_size; (void)ws_size;

    const float* x  = (const float*)d_in[0];
    const int*   ei = (const int*)d_in[1];
    const float* W1 = (const float*)d_in[2];  const float* b1 = (const float*)d_in[3];
    const float* W2 = (const float*)d_in[4];  const float* b2 = (const float*)d_in[5];
    const float* W3 = (const float*)d_in[6];  const float* b3 = (const float*)d_in[7];
    const float* W4 = (const float*)d_in[8];  const float* b4 = (const float*)d_in[9];
    const float* W5 = (const float*)d_in[10]; const float* b5 = (const float*)d_in[11];
    const float* W6 = (const float*)d_in[12]; const float* b6 = (const float*)d_in[13];

    const int n = in_sizes[0] / 64;   // 100000
    const int E = in_sizes[1] / 2;    // 1600000
    const int* src = ei;
    const int* dst = ei + E;

    float* out  = (float*)d_out;
    float* xrec = out;                       // [n,64]
    float* z    = out + (size_t)n * 64;      // [n,32]

    char* ws = (char*)d_ws;
    size_t off = 0;
    float*  dinv = (float*)(ws + off);  off += align256((size_t)n * 4);
    int*    cur  = (int*)(ws + off);    off += align256((size_t)(n + NB) * 4);
    int*    csr  = (int*)(ws + off);    off += align256((size_t)n * PAD * 4);
    __half* sA   = (__half*)(ws + off); off += align256((size_t)n * 64 * 2);
    __half* sB   = (__half*)(ws + off); off += align256((size_t)n * 64 * 2);
    __half* sZ   = (__half*)(ws + off); off += align256((size_t)n * 32 * 2);
    __half* xh   = sB;        // overlay: xh dead after layer 1
    int*    qcnt = cur + n;   // NB ints in cur's allocation
    int*    queue = (int*)sA; // overlay: dead before layer 1 writes sA
    const int BW   = (n + NB - 1) / NB;        // 391 nodes per bucket (<512)
    const int qcap = E / NB + 1024;            // mean 6250 + >6 sigma slack
    // NB*qcap*4 = 7.45MB <= sizeof(sA) = 12.8MB

    const int B = 256;
    const int fGrid = (n + 63) / 64;          // 16 nodes/wave, 4 waves/block
    const int nch = (E + 4095) / 4096;

    // ---- CSR build: bucket -> per-bucket LDS counting scatter -> prescale ----
    hipMemsetAsync(qcnt, 0, NB * 4, stream);
    bucket_kernel<<<nch, B, 0, stream>>>(src, dst, E, BW, qcnt, queue, qcap);
    scatter_lds_kernel<<<NB, B, 0, stream>>>(qcnt, queue, qcap, n, BW, cur, csr);
    scale_cast_kernel<<<(n * 16 + B - 1) / B, B, 0, stream>>>(x, cur, dinv, xh, n);

    // ---- Layer 1: relu((A x) W1 + b1) -> sA (prescaled fp16) ----
    fused_mfma<64, 64, true, true, false><<<fGrid, B, 0, stream>>>(
        xh, W1, b1, cur, csr, dinv, sA, nullptr, n);
    // ---- Layer 2 -> sB ----
    fused_mfma<64, 64, true, true, false><<<fGrid, B, 0, stream>>>(
        sA, W2, b2, cur, csr, dinv, sB, nullptr, n);
    // ---- Layer 3: 64->32, no relu; z fp32 + prescaled sZ ----
    fused_mfma<64, 32, false, true, true><<<fGrid, B, 0, stream>>>(
        sB, W3, b3, cur, csr, dinv, sZ, z, n);
    // ---- Layer 4: 32->64 relu -> sA ----
    fused_mfma<32, 64, true, true, false><<<fGrid, B, 0, stream>>>(
        sZ, W4, b4, cur, csr, dinv, sA, nullptr, n);
    // ---- Layer 5 -> sB ----
    fused_mfma<64, 64, true, true, false><<<fGrid, B, 0, stream>>>(
        sA, W5, b5, cur, csr, dinv, sB, nullptr, n);
    // ---- Layer 6: no relu -> xrec (fp32) ----
    fused_mfma<64, 64, false, false, true><<<fGrid, B, 0, stream>>>(
        sB, W6, b6, cur, csr, dinv, nullptr, xrec, n);
}

// Round 8
// 349.903 us; speedup vs baseline: 1.1497x; 1.0115x over previous
//
#include <hip/hip_runtime.h>
#include <hip/hip_fp16.h>

// GCN autoencoder, R15: raise gather MLP in fused_mfma.
// R14's fused layer was latency-bound (FETCH 94MB ~= compulsory 8-XCD floor,
// but only ~2TB/s; VGPR 60 -> ~5 outstanding gathers/wave; LDS 27.6KB -> 5
// blocks/CU; 16-way bank conflict on epilogue A-reads). Now: (a) aS handoff
// stored as fp16 in unpadded 128B rows with XOR-swizzled 16B blocks (LDS
// 16KB/block, conflict-free MFMA operand reads), (b) gathers explicitly
// batched 8-at-a-time into v[8] (8 outstanding misses/wave by construction).
// CSR build (bucket + LDS counting scatter) unchanged from R14.

typedef _Float16 f16x8 __attribute__((ext_vector_type(8)));
typedef float f32x4 __attribute__((ext_vector_type(4)));

static inline size_t align256(size_t x) { return (x + 255) & ~(size_t)255; }

constexpr int PAD = 64;   // csr slots per node (Poisson(16) max-deg ~44)
constexpr int NB  = 256;  // dst buckets (~391 nodes each)

// ---- Phase A: bucket edges by dst range ----
__global__ void __launch_bounds__(256) bucket_kernel(
        const int* __restrict__ src, const int* __restrict__ dst, int E, int BW,
        int* __restrict__ qcnt, int* __restrict__ queue, int qcap) {
    __shared__ int hist[NB];
    __shared__ int gbase[NB];
    __shared__ int cursor[NB];
    const int tid = threadIdx.x;
    hist[tid] = 0; cursor[tid] = 0;          // blockDim == NB == 256
    __syncthreads();

    const int e0 = blockIdx.x * 4096;
    int pk[16], bk[16];
#pragma unroll
    for (int l = 0; l < 16; ++l) {
        int e = e0 + l * 256 + tid;
        bool v = e < E;
        int d = v ? __builtin_nontemporal_load(dst + e) : 0;
        int s = v ? __builtin_nontemporal_load(src + e) : 0;
        int b = (int)((unsigned)d / (unsigned)BW);
        pk[l] = ((d - b * BW) << 17) | s;
        bk[l] = v ? b : -1;
        if (v) atomicAdd(&hist[b], 1);       // LDS
    }
    __syncthreads();
    int h = hist[tid];
    gbase[tid] = h ? atomicAdd(&qcnt[tid], h) : 0;   // 1 global atomic/bucket
    __syncthreads();
#pragma unroll
    for (int l = 0; l < 16; ++l) {
        if (bk[l] >= 0) {
            int b = bk[l];
            int r = gbase[b] + atomicAdd(&cursor[b], 1);   // LDS
            if (r < qcap) queue[(size_t)b * qcap + r] = pk[l];
        }
    }
}

// ---- Phase B: one block per bucket, LDS counters, plain csr stores ----
__global__ void __launch_bounds__(256) scatter_lds_kernel(
        const int* __restrict__ qcnt, const int* __restrict__ queue, int qcap,
        int n, int BW, int* __restrict__ cur, int* __restrict__ csr) {
    __shared__ int cnt[512];                 // BW <= 512
    const int b = blockIdx.x;
    const int node0 = b * BW;
    const int nn = min(BW, n - node0);
    if (nn <= 0) return;
    for (int t = threadIdx.x; t < nn; t += 256) cnt[t] = 0;
    __syncthreads();
    const int qn = min(qcnt[b], qcap);
    const int* q = queue + (size_t)b * qcap;
    for (int i = threadIdx.x; i < qn; i += 256) {
        int u = q[i];
        int dl = u >> 17;
        int s = u & 0x1FFFF;
        int pos = atomicAdd(&cnt[dl], 1);    // LDS, on-CU
        if (pos < PAD) csr[(size_t)(node0 + dl) * PAD + pos] = s;
    }
    __syncthreads();
    for (int t = threadIdx.x; t < nn; t += 256) cur[node0 + t] = cnt[t];
}

// dinv[i] = rsqrt(deg+1); xh[i,:] = (half)(dinv[i] * x[i,:])
__global__ void scale_cast_kernel(const float* __restrict__ x, const int* __restrict__ cnt,
                                  float* __restrict__ dinv, __half* __restrict__ xh, int n) {
    int t = blockIdx.x * blockDim.x + threadIdx.x;   // over n*16 float4s
    if (t >= n * 16) return;
    int node = t >> 4;
    float d = rsqrtf((float)cnt[node] + 1.0f);
    if ((t & 15) == 0) dinv[node] = d;
    float4 v = ((const float4*)x)[t];
    __half2* o = (__half2*)xh;
    o[t * 2 + 0] = __floats2half2_rn(v.x * d, v.y * d);
    o[t * 2 + 1] = __floats2half2_rn(v.z * d, v.w * d);
}

__device__ __forceinline__ void accum8(float4& a0, float4& a1, const uint4& u, float w) {
    const __half2* h = reinterpret_cast<const __half2*>(&u);
    float2 f0 = __half22float2(h[0]);
    float2 f1 = __half22float2(h[1]);
    float2 f2 = __half22float2(h[2]);
    float2 f3 = __half22float2(h[3]);
    a0.x = fmaf(w, f0.x, a0.x); a0.y = fmaf(w, f0.y, a0.y);
    a0.z = fmaf(w, f1.x, a0.z); a0.w = fmaf(w, f1.y, a0.w);
    a1.x = fmaf(w, f2.x, a1.x); a1.y = fmaf(w, f2.y, a1.y);
    a1.z = fmaf(w, f3.x, a1.z); a1.w = fmaf(w, f3.y, a1.w);
}

// Fused GCN layer, prescaled fp16 input, padded CSR, MFMA epilogue.
// aS handoff + W both in LDS as fp16, unpadded rows, XOR-swizzled 16B blocks
// (block b of row r lives at b^(r&(BLK-1))): MFMA operand reads ~2 lanes/bank.
template <int K, int M, bool RELU, bool WS, bool WR>
__global__ void __launch_bounds__(256) fused_mfma(
        const __half* __restrict__ in, const float* __restrict__ W,
        const float* __restrict__ bias,
        const int* __restrict__ cnt, const int* __restrict__ csr,
        const float* __restrict__ dinv,
        __half* __restrict__ outS, float* __restrict__ outR, int n) {
    constexpr int LPR = K / 8;       // lanes per feature row (uint4 = 8 halves)
    constexpr int GRP = 64 / LPR;    // nodes per gather round (8 or 16)
    constexpr int ROUNDS = 16 / GRP; // rounds to fill 16-node batch (2 or 1)
    constexpr int KT = K / 32;       // MFMA K-tiles
    constexpr int NT = M / 16;       // MFMA N-tiles
    constexpr int BLK = K / 8;       // 16B blocks per row (8 or 4)

    __shared__ _Float16 Whs[M * K];          // W transposed fp16, swizzled
    __shared__ _Float16 aSh[4][16 * K];      // per-wave handoff, swizzled

    const int wv = threadIdx.x >> 6, lane = threadIdx.x & 63;

    // stage W transposed+fp16+swizzled into LDS once per block
    for (int t = threadIdx.x; t < K * M; t += 256) {
        int k = t / M, j = t % M;            // W row-major [K][M]
        Whs[j * K + (((k >> 3) ^ (j & (BLK - 1))) << 3) + (k & 7)] = (_Float16)W[t];
    }
    __syncthreads();   // all waves reach this before any early-out

    const int i0 = (blockIdx.x * 4 + wv) * 16;
    if (i0 >= n) return;             // n % 16 == 0: active waves fully in-bounds

    const int g = lane / LPR, sub = lane % LPR;
    const uint4* in16 = (const uint4*)in;

#pragma unroll
    for (int r = 0; r < ROUNDS; ++r) {
        const int nd = r * GRP + g;              // node slot in the 16-batch
        const int node = i0 + nd;
        const int deg = min(cnt[node], PAD);
        const float dv = dinv[node];
        const int base = node * PAD;
        float4 a0 = make_float4(0.f, 0.f, 0.f, 0.f), a1 = a0;
        accum8(a0, a1, in16[(size_t)node * LPR + sub], 1.0f);  // self loop

        // 4 chunks x 8 slots: batch-load 8 gathers, then accumulate
#pragma unroll
        for (int c = 0; c < 4; ++c) {
            int4 iA = *(const int4*)&csr[base + c * 8];
            int4 iB = *(const int4*)&csr[base + c * 8 + 4];
            int s[8] = {iA.x, iA.y, iA.z, iA.w, iB.x, iB.y, iB.z, iB.w};
            uint4 v[8];
            float w[8];
#pragma unroll
            for (int l = 0; l < 8; ++l) {
                bool m = (c * 8 + l) < deg;
                int si = m ? s[l] : node;        // dummy: own row, cache-hot
                w[l] = m ? 1.0f : 0.0f;
                v[l] = in16[(size_t)si * LPR + sub];
            }
#pragma unroll
            for (int l = 0; l < 8; ++l) accum8(a0, a1, v[l], w[l]);
        }
        // rare tail: deg > 32 (P ~ 1.5e-4 per node)
        for (int t = 8; t < 16; ++t) {
            if (!__any(t * 4 < deg)) break;
            int4 idx = *(const int4*)&csr[base + t * 4];
            int s4[4] = {idx.x, idx.y, idx.z, idx.w};
#pragma unroll
            for (int l = 0; l < 4; ++l) {
                bool m = (t * 4 + l) < deg;
                int si = m ? s4[l] : node;
                uint4 v = in16[(size_t)si * LPR + sub];
                accum8(a0, a1, v, m ? 1.0f : 0.0f);
            }
        }
        // fold dinv[dst]; convert + store swizzled fp16 handoff (block 'sub')
        f16x8 h;
        h[0] = (_Float16)(a0.x * dv); h[1] = (_Float16)(a0.y * dv);
        h[2] = (_Float16)(a0.z * dv); h[3] = (_Float16)(a0.w * dv);
        h[4] = (_Float16)(a1.x * dv); h[5] = (_Float16)(a1.y * dv);
        h[6] = (_Float16)(a1.z * dv); h[7] = (_Float16)(a1.w * dv);
        *(f16x8*)&aSh[wv][nd * K + ((sub ^ (nd & (BLK - 1))) << 3)] = h;
    }
    // per-wave LDS: compiler inserts lgkmcnt waits; no barrier needed

    // ---- MFMA epilogue: y[16 x M] = aSh[16 x K] @ W[K x M] ----
    const int mm = lane & 15, q = lane >> 4;
    const int sw = mm & (BLK - 1);
    f32x4 acc[NT];
#pragma unroll
    for (int nt = 0; nt < NT; ++nt) acc[nt] = (f32x4){0.f, 0.f, 0.f, 0.f};
#pragma unroll
    for (int kt = 0; kt < KT; ++kt) {
        const int lb = kt * 4 + q;           // logical 16B block
        f16x8 a = *(const f16x8*)&aSh[wv][mm * K + ((lb ^ sw) << 3)];
#pragma unroll
        for (int nt = 0; nt < NT; ++nt) {
            f16x8 b = *(const f16x8*)&Whs[(nt * 16 + mm) * K + ((lb ^ sw) << 3)];
            acc[nt] = __builtin_amdgcn_mfma_f32_16x16x32_f16(a, b, acc[nt], 0, 0, 0);
        }
    }

    float dv4[4];
    if constexpr (WS) {
#pragma unroll
        for (int r = 0; r < 4; ++r) dv4[r] = dinv[i0 + q * 4 + r];
    }
#pragma unroll
    for (int nt = 0; nt < NT; ++nt) {
        float bv = bias[nt * 16 + mm];
#pragma unroll
        for (int r = 0; r < 4; ++r) {
            int node = i0 + q * 4 + r;
            float y = acc[nt][r] + bv;
            if (RELU) y = fmaxf(y, 0.0f);
            if (WR) outR[(size_t)node * M + nt * 16 + mm] = y;
            if (WS) outS[(size_t)node * M + nt * 16 + mm] = __float2half_rn(dv4[r] * y);
        }
    }
}

extern "C" void kernel_launch(void* const* d_in, const int* in_sizes, int n_in,
                              void* d_out, int out_size, void* d_ws, size_t ws_size,
                              hipStream_t stream) {
    (void)n_in; (void)out_size; (void)ws_size;

    const float* x  = (const float*)d_in[0];
    const int*   ei = (const int*)d_in[1];
    const float* W1 = (const float*)d_in[2];  const float* b1 = (const float*)d_in[3];
    const float* W2 = (const float*)d_in[4];  const float* b2 = (const float*)d_in[5];
    const float* W3 = (const float*)d_in[6];  const float* b3 = (const float*)d_in[7];
    const float* W4 = (const float*)d_in[8];  const float* b4 = (const float*)d_in[9];
    const float* W5 = (const float*)d_in[10]; const float* b5 = (const float*)d_in[11];
    const float* W6 = (const float*)d_in[12]; const float* b6 = (const float*)d_in[13];

    const int n = in_sizes[0] / 64;   // 100000
    const int E = in_sizes[1] / 2;    // 1600000
    const int* src = ei;
    const int* dst = ei + E;

    float* out  = (float*)d_out;
    float* xrec = out;                       // [n,64]
    float* z    = out + (size_t)n * 64;      // [n,32]

    char* ws = (char*)d_ws;
    size_t off = 0;
    float*  dinv = (float*)(ws + off);  off += align256((size_t)n * 4);
    int*    cur  = (int*)(ws + off);    off += align256((size_t)(n + NB) * 4);
    int*    csr  = (int*)(ws + off);    off += align256((size_t)n * PAD * 4);
    __half* sA   = (__half*)(ws + off); off += align256((size_t)n * 64 * 2);
    __half* sB   = (__half*)(ws + off); off += align256((size_t)n * 64 * 2);
    __half* sZ   = (__half*)(ws + off); off += align256((size_t)n * 32 * 2);
    __half* xh   = sB;        // overlay: xh dead after layer 1
    int*    qcnt = cur + n;   // NB ints in cur's allocation
    int*    queue = (int*)sA; // overlay: dead before layer 1 writes sA
    const int BW   = (n + NB - 1) / NB;        // 391 nodes per bucket (<512)
    const int qcap = E / NB + 1024;            // mean 6250 + >6 sigma slack

    const int B = 256;
    const int fGrid = (n + 63) / 64;          // 16 nodes/wave, 4 waves/block
    const int nch = (E + 4095) / 4096;

    // ---- CSR build: bucket -> per-bucket LDS counting scatter -> prescale ----
    hipMemsetAsync(qcnt, 0, NB * 4, stream);
    bucket_kernel<<<nch, B, 0, stream>>>(src, dst, E, BW, qcnt, queue, qcap);
    scatter_lds_kernel<<<NB, B, 0, stream>>>(qcnt, queue, qcap, n, BW, cur, csr);
    scale_cast_kernel<<<(n * 16 + B - 1) / B, B, 0, stream>>>(x, cur, dinv, xh, n);

    // ---- Layer 1: relu((A x) W1 + b1) -> sA (prescaled fp16) ----
    fused_mfma<64, 64, true, true, false><<<fGrid, B, 0, stream>>>(
        xh, W1, b1, cur, csr, dinv, sA, nullptr, n);
    // ---- Layer 2 -> sB ----
    fused_mfma<64, 64, true, true, false><<<fGrid, B, 0, stream>>>(
        sA, W2, b2, cur, csr, dinv, sB, nullptr, n);
    // ---- Layer 3: 64->32, no relu; z fp32 + prescaled sZ ----
    fused_mfma<64, 32, false, true, true><<<fGrid, B, 0, stream>>>(
        sB, W3, b3, cur, csr, dinv, sZ, z, n);
    // ---- Layer 4: 32->64 relu -> sA ----
    fused_mfma<32, 64, true, true, false><<<fGrid, B, 0, stream>>>(
        sZ, W4, b4, cur, csr, dinv, sA, nullptr, n);
    // ---- Layer 5 -> sB ----
    fused_mfma<64, 64, true, true, false><<<fGrid, B, 0, stream>>>(
        sA, W5, b5, cur, csr, dinv, sB, nullptr, n);
    // ---- Layer 6: no relu -> xrec (fp32) ----
    fused_mfma<64, 64, false, false, true><<<fGrid, B, 0, stream>>>(
        sB, W6, b6, cur, csr, dinv, nullptr, xrec, n);
}